// Round 8
// baseline (491.872 us; speedup 1.0000x reference)
//
#include <hip/hip_runtime.h>
#include <hip/hip_cooperative_groups.h>
#include <hip/hip_bf16.h>
#include <cstdint>

namespace cg = cooperative_groups;

#define DEV __device__ __forceinline__

typedef __attribute__((ext_vector_type(8))) short short8;
typedef __attribute__((ext_vector_type(4))) float f32x4;
typedef __attribute__((ext_vector_type(8))) unsigned short us8;

DEV unsigned short f2bf(float x) {
    unsigned int u = __float_as_uint(x);
    unsigned int r = (u + 0x7FFFu + ((u >> 16) & 1u)) >> 16;
    return (unsigned short)r;
}
DEV float bf2f(unsigned short h) { return __uint_as_float(((unsigned int)h) << 16); }

#define LL 4096
#define DM 256
#define DH 128
#define CH1 32
#define NCH 128
#define LOG2E 1.44269504088896f

// Cooperative megakernel. Grid-stride in every phase -> correct at any grid size
// (we launch 512 or 256). Static LDS capped at 32KB so even a 64KB-basis
// occupancy calc admits 2 blocks/CU (r7's 60.9KB LDS made the coop launch
// validator reject grid=512 -> kernel never ran).
__global__ __launch_bounds__(256, 2) void mega(
    const float* __restrict__ u0, const float* __restrict__ u1,
    const float* __restrict__ inw, const float* __restrict__ cxw,
    const float* __restrict__ czw, const float* __restrict__ xpw,
    const float* __restrict__ dtw, const float* __restrict__ dtb,
    const float* __restrict__ alog, const float* __restrict__ Dp,
    const float* __restrict__ outw,
    unsigned short* __restrict__ xz, unsigned short* __restrict__ xfb,
    float* __restrict__ delta, float* __restrict__ BC,
    unsigned short* __restrict__ catb, float* __restrict__ P,
    float* __restrict__ H, float* __restrict__ An,
    unsigned short* __restrict__ Wcat, float* __restrict__ outp)
{
    cg::grid_group grid = cg::this_grid();
    __shared__ __align__(16) char smem[32768];
    const int t = threadIdx.x;
    const int b = blockIdx.x;
    const int G = gridDim.x;
    const int lane = t & 63, wv = t >> 6;
    const int lr = lane & 15, lk = (lane >> 4) * 8;

    // -------- prep (blocks 0,1): An = -exp(A_log); Wcat = [dtw@xw_dt ; xw_BC] --------
    if (b == 0) {
        for (int q = t; q < 2048; q += 256) An[q] = -__expf(alog[q]);
    } else if (b == 1) {
        int d = t >> 1, k0 = (t & 1) * 64;
        float dr[16];
        #pragma unroll
        for (int r = 0; r < 16; ++r) dr[r] = dtw[d * 16 + r];
        for (int k = 0; k < 64; ++k) {
            float a = 0.f;
            #pragma unroll
            for (int r = 0; r < 16; ++r) a = fmaf(dr[r], xpw[r * 128 + k0 + k], a);
            Wcat[d * 128 + k0 + k] = f2bf(a);
        }
        for (int q = t * 16; q < t * 16 + 16; ++q) {
            int row = q >> 7, col = q & 127;
            Wcat[(128 + row) * 128 + col] = f2bf(xpw[(16 + row) * 128 + col]);
        }
    }

    // ================= Phase A: gemm1 (fp32 staged->bf16) -> xz bf16 ===================
    {
        unsigned short* As = (unsigned short*)smem;   // 128*32 = 8KB
        unsigned short* Bs = As + 4096;               // 8KB
        const int wm = (wv & 1) * 64, wn = (wv >> 1) * 64;
        for (int tile = b; tile < 512; tile += G) {
            const int m0 = (tile & 255) * 128, n0 = (tile >> 8) * 128;
            const float* Abase = (m0 < 16384) ? (u0 + (size_t)m0 * 256)
                                              : (u1 + (size_t)(m0 - 16384) * 256);
            f32x4 acc[4][4] = {};
            for (int kt = 0; kt < 8; ++kt) {
                const int k0 = kt * 32;
                #pragma unroll
                for (int j = 0; j < 2; ++j) {
                    int c = t + j * 256;
                    int row = c >> 2, col = (c & 3) * 8;
                    f32x4 a0 = *(const f32x4*)(Abase + (size_t)row * 256 + k0 + col);
                    f32x4 a1 = *(const f32x4*)(Abase + (size_t)row * 256 + k0 + col + 4);
                    f32x4 b0 = *(const f32x4*)(inw + (size_t)(n0 + row) * 256 + k0 + col);
                    f32x4 b1 = *(const f32x4*)(inw + (size_t)(n0 + row) * 256 + k0 + col + 4);
                    short8 va = { (short)f2bf(a0.x), (short)f2bf(a0.y), (short)f2bf(a0.z), (short)f2bf(a0.w),
                                  (short)f2bf(a1.x), (short)f2bf(a1.y), (short)f2bf(a1.z), (short)f2bf(a1.w) };
                    short8 vb = { (short)f2bf(b0.x), (short)f2bf(b0.y), (short)f2bf(b0.z), (short)f2bf(b0.w),
                                  (short)f2bf(b1.x), (short)f2bf(b1.y), (short)f2bf(b1.z), (short)f2bf(b1.w) };
                    *(short8*)&As[row * 32 + col] = va;
                    *(short8*)&Bs[row * 32 + col] = vb;
                }
                __syncthreads();
                short8 av[4], bv[4];
                #pragma unroll
                for (int i = 0; i < 4; ++i) av[i] = *(const short8*)&As[(wm + i * 16 + lr) * 32 + lk];
                #pragma unroll
                for (int i = 0; i < 4; ++i) bv[i] = *(const short8*)&Bs[(wn + i * 16 + lr) * 32 + lk];
                #pragma unroll
                for (int i = 0; i < 4; ++i)
                    #pragma unroll
                    for (int j = 0; j < 4; ++j)
                        acc[i][j] = __builtin_amdgcn_mfma_f32_16x16x32_bf16(av[i], bv[j], acc[i][j], 0, 0, 0);
                __syncthreads();
            }
            #pragma unroll
            for (int i = 0; i < 4; ++i)
                #pragma unroll
                for (int j = 0; j < 4; ++j) {
                    int r0 = m0 + wm + i * 16 + (lane >> 4) * 4;
                    int cc = n0 + wn + j * 16 + lr;
                    #pragma unroll
                    for (int r = 0; r < 4; ++r)
                        xz[(size_t)(r0 + r) * 256 + cc] = f2bf(acc[i][j][r]);
                }
        }
    }
    grid.sync();

    // ================= Phase B: depthwise conv(3) + SiLU -> xfb bf16, catb z ===========
    for (int gid = b * 256 + t; gid < 524288; gid += G * 256) {
        int g = gid & 15;
        int l = (gid >> 4) & 4095;
        int sb = gid >> 16;
        size_t row = (size_t)sb * LL + l;
        const unsigned short* bp = xz + row * DM;
        int cx = g * 8;
        us8 zz = (us8)0;
        us8 xm = (l > 0)    ? *(const us8*)(bp - DM + cx)       : zz;
        us8 x0 = *(const us8*)(bp + cx);
        us8 xp = (l < 4095) ? *(const us8*)(bp + DM + cx)       : zz;
        us8 zm = (l > 0)    ? *(const us8*)(bp - DM + 128 + cx) : zz;
        us8 z0 = *(const us8*)(bp + 128 + cx);
        us8 zp = (l < 4095) ? *(const us8*)(bp + DM + 128 + cx) : zz;
        us8 xo, zo;
        #pragma unroll
        for (int j = 0; j < 8; ++j) {
            int c = cx + j;
            float xv = bf2f(xm[j]) * cxw[c * 3] + bf2f(x0[j]) * cxw[c * 3 + 1] + bf2f(xp[j]) * cxw[c * 3 + 2];
            float zv = bf2f(zm[j]) * czw[c * 3] + bf2f(z0[j]) * czw[c * 3 + 1] + bf2f(zp[j]) * czw[c * 3 + 2];
            xv = xv / (1.f + __expf(-xv));
            zv = zv / (1.f + __expf(-zv));
            xo[j] = f2bf(xv);
            zo[j] = f2bf(zv);
        }
        *(us8*)&xfb[row * DH + cx] = xo;
        *(us8*)&catb[row * DM + 128 + cx] = zo;
    }
    grid.sync();

    // ================= Phase C: proj MFMA (A staged 17.4KB; Wcat read from L1/L2) ======
    {
        unsigned short* As = (unsigned short*)smem;   // 64*136*2 = 17,408 B
        for (int tile = b; tile < 512; tile += G) {
            const int m0 = tile * 64;
            for (int q = t; q < 1024; q += 256) {
                int row = q >> 4, col = (q & 15) * 8;
                *(short8*)&As[row * 136 + col] = *(const short8*)(xfb + (size_t)(m0 + row) * 128 + col);
            }
            __syncthreads();
            f32x4 acc[10] = {};
            #pragma unroll
            for (int kb = 0; kb < 4; ++kb) {
                short8 av = *(const short8*)&As[(wv * 16 + lr) * 136 + kb * 32 + lk];
                #pragma unroll
                for (int j = 0; j < 10; ++j) {
                    short8 bv = *(const short8*)(Wcat + (j * 16 + lr) * 128 + kb * 32 + lk);
                    acc[j] = __builtin_amdgcn_mfma_f32_16x16x32_bf16(av, bv, acc[j], 0, 0, 0);
                }
            }
            #pragma unroll
            for (int j = 0; j < 10; ++j) {
                int r0 = m0 + wv * 16 + (lane >> 4) * 4;
                int col = j * 16 + lr;
                if (col < 128) {
                    float bias = dtb[col];
                    #pragma unroll
                    for (int r = 0; r < 4; ++r) {
                        float v = acc[j][r] + bias;
                        float sp = (v > 20.f) ? v : log1pf(__expf(v));
                        delta[(size_t)(r0 + r) * DH + col] = sp;
                    }
                } else {
                    #pragma unroll
                    for (int r = 0; r < 4; ++r)
                        BC[(size_t)(r0 + r) * 32 + (col - 128)] = acc[j][r];
                }
            }
            __syncthreads();
        }
    }
    grid.sync();

    // ================= Phase D: scan_p1 — one chunk/iter, n split across lane pairs ====
    {
        float* dt_s = (float*)smem;                            // 16KB
        unsigned short* u_s = (unsigned short*)(smem + 16384); // 8KB
        float* b_s = (float*)(smem + 24576);                   // 2KB -> 26.6KB
        const int d = wv * 32 + (lane >> 1), nh8 = (lane & 1) * 8;
        float Ar[8];
        #pragma unroll
        for (int n = 0; n < 8; ++n) Ar[n] = An[d * 16 + nh8 + n] * LOG2E;
        for (int c = b; c < 1024; c += G) {
            int sb = c >> 7, ch = c & 127;
            size_t rb = (size_t)sb * LL + (size_t)ch * CH1;
            for (int q = t; q < 1024; q += 256) {
                int row = q >> 5, c4 = (q & 31) * 4;
                *(f32x4*)&dt_s[row * 128 + c4] = *(const f32x4*)&delta[(rb + row) * DH + c4];
            }
            for (int q = t; q < 512; q += 256) {
                int row = q >> 4, c8 = (q & 15) * 8;
                *(us8*)&u_s[row * 128 + c8] = *(const us8*)&xfb[(rb + row) * DH + c8];
            }
            if (t < 128) {
                int row = t >> 2, c4 = (t & 3) * 4;
                *(f32x4*)&b_s[row * 16 + c4] = *(const f32x4*)&BC[(rb + row) * 32 + c4];
            }
            __syncthreads();
            float h[8], p[8];
            #pragma unroll
            for (int n = 0; n < 8; ++n) { h[n] = 0.f; p[n] = 1.f; }
            #pragma unroll 4
            for (int i = 0; i < CH1; ++i) {
                float dt = dt_s[i * 128 + d];
                float du = dt * bf2f(u_s[i * 128 + d]);
                #pragma unroll
                for (int n = 0; n < 8; ++n) {
                    float a = exp2f(dt * Ar[n]);
                    h[n] = fmaf(a, h[n], du * b_s[i * 16 + nh8 + n]);
                    p[n] *= a;
                }
            }
            size_t ob = (((size_t)sb * NCH + ch) * 128 + d) * 16 + nh8;
            *(f32x4*)&P[ob]     = *(f32x4*)&p[0];
            *(f32x4*)&P[ob + 4] = *(f32x4*)&p[4];
            *(f32x4*)&H[ob]     = *(f32x4*)&h[0];
            *(f32x4*)&H[ob + 4] = *(f32x4*)&h[4];
            __syncthreads();
        }
    }
    grid.sync();

    // ================= Phase E: chunk-prefix, one (sb,d) chain per iteration ===========
    {
        float* Ps = (float*)smem;            // 8KB
        float* Hs = (float*)(smem + 8192);   // 8KB
        for (int q2 = b; q2 < 1024; q2 += G) {
            int sb = q2 >> 7, d = q2 & 127;
            for (int q = t; q < 512; q += 256) {
                int ch = q >> 2, c4 = (q & 3) * 4;
                size_t g = (((size_t)sb * NCH + ch) * 128 + d) * 16 + c4;
                *(f32x4*)&Ps[ch * 16 + c4] = *(const f32x4*)&P[g];
                *(f32x4*)&Hs[ch * 16 + c4] = *(const f32x4*)&H[g];
            }
            __syncthreads();
            if (t < 16) {
                float hin = 0.f;
                for (int c = 0; c < NCH; ++c) {
                    float pp = Ps[c * 16 + t], hl = Hs[c * 16 + t];
                    Hs[c * 16 + t] = hin;
                    hin = fmaf(pp, hin, hl);
                }
            }
            __syncthreads();
            for (int q = t; q < 512; q += 256) {
                int ch = q >> 2, c4 = (q & 3) * 4;
                size_t g = (((size_t)sb * NCH + ch) * 128 + d) * 16 + c4;
                *(f32x4*)&H[g] = *(const f32x4*)&Hs[ch * 16 + c4];
            }
            __syncthreads();
        }
    }
    grid.sync();

    // ================= Phase F: scan_p3 replay + y emit ================================
    {
        float* dt_s = (float*)smem;
        unsigned short* u_s = (unsigned short*)(smem + 16384);
        float* b_s = (float*)(smem + 24576);                   // 2KB
        float* c_s = (float*)(smem + 26624);                   // 2KB -> 28.7KB
        const int d = wv * 32 + (lane >> 1), nh8 = (lane & 1) * 8;
        float Ar[8];
        #pragma unroll
        for (int n = 0; n < 8; ++n) Ar[n] = An[d * 16 + nh8 + n] * LOG2E;
        float Dv = Dp[d];
        for (int c = b; c < 1024; c += G) {
            int sb = c >> 7, ch = c & 127;
            size_t rb = (size_t)sb * LL + (size_t)ch * CH1;
            for (int q = t; q < 1024; q += 256) {
                int row = q >> 5, c4 = (q & 31) * 4;
                *(f32x4*)&dt_s[row * 128 + c4] = *(const f32x4*)&delta[(rb + row) * DH + c4];
            }
            for (int q = t; q < 512; q += 256) {
                int row = q >> 4, c8 = (q & 15) * 8;
                *(us8*)&u_s[row * 128 + c8] = *(const us8*)&xfb[(rb + row) * DH + c8];
            }
            if (t < 128) {
                int row = t >> 2, c4 = (t & 3) * 4;
                *(f32x4*)&b_s[row * 16 + c4] = *(const f32x4*)&BC[(rb + row) * 32 + c4];
                *(f32x4*)&c_s[row * 16 + c4] = *(const f32x4*)&BC[(rb + row) * 32 + 16 + c4];
            }
            __syncthreads();
            size_t ob = (((size_t)sb * NCH + ch) * 128 + d) * 16 + nh8;
            float h[8];
            *(f32x4*)&h[0] = *(const f32x4*)&H[ob];
            *(f32x4*)&h[4] = *(const f32x4*)&H[ob + 4];
            #pragma unroll 2
            for (int i = 0; i < CH1; ++i) {
                float dt = dt_s[i * 128 + d];
                float uu = bf2f(u_s[i * 128 + d]);
                float du = dt * uu;
                float y0 = 0.f, y1 = 0.f;
                #pragma unroll
                for (int n = 0; n < 8; n += 2) {
                    float a0 = exp2f(dt * Ar[n]);
                    float a1 = exp2f(dt * Ar[n + 1]);
                    h[n]     = fmaf(a0, h[n],     du * b_s[i * 16 + nh8 + n]);
                    h[n + 1] = fmaf(a1, h[n + 1], du * b_s[i * 16 + nh8 + n + 1]);
                    y0 = fmaf(h[n],     c_s[i * 16 + nh8 + n],     y0);
                    y1 = fmaf(h[n + 1], c_s[i * 16 + nh8 + n + 1], y1);
                }
                float y = y0 + y1;
                y += __shfl_xor(y, 1);
                if (nh8 == 0) catb[(rb + i) * DM + d] = f2bf(y + uu * Dv);
            }
            __syncthreads();
        }
    }
    grid.sync();

    // ================= Phase G: gemm2 -> out fp32 ======================================
    {
        unsigned short* As = (unsigned short*)smem;
        unsigned short* Bs = As + 4096;
        const int wm = (wv & 1) * 64, wn = (wv >> 1) * 64;
        for (int tile = b; tile < 512; tile += G) {
            const int m0 = (tile & 255) * 128, n0 = (tile >> 8) * 128;
            f32x4 acc[4][4] = {};
            for (int kt = 0; kt < 8; ++kt) {
                const int k0 = kt * 32;
                #pragma unroll
                for (int j = 0; j < 2; ++j) {
                    int c = t + j * 256;
                    int row = c >> 2, col = (c & 3) * 8;
                    short8 va = *(const short8*)(catb + (size_t)(m0 + row) * 256 + k0 + col);
                    f32x4 b0 = *(const f32x4*)(outw + (size_t)(n0 + row) * 256 + k0 + col);
                    f32x4 b1 = *(const f32x4*)(outw + (size_t)(n0 + row) * 256 + k0 + col + 4);
                    short8 vb = { (short)f2bf(b0.x), (short)f2bf(b0.y), (short)f2bf(b0.z), (short)f2bf(b0.w),
                                  (short)f2bf(b1.x), (short)f2bf(b1.y), (short)f2bf(b1.z), (short)f2bf(b1.w) };
                    *(short8*)&As[row * 32 + col] = va;
                    *(short8*)&Bs[row * 32 + col] = vb;
                }
                __syncthreads();
                short8 av[4], bv[4];
                #pragma unroll
                for (int i = 0; i < 4; ++i) av[i] = *(const short8*)&As[(wm + i * 16 + lr) * 32 + lk];
                #pragma unroll
                for (int i = 0; i < 4; ++i) bv[i] = *(const short8*)&Bs[(wn + i * 16 + lr) * 32 + lk];
                #pragma unroll
                for (int i = 0; i < 4; ++i)
                    #pragma unroll
                    for (int j = 0; j < 4; ++j)
                        acc[i][j] = __builtin_amdgcn_mfma_f32_16x16x32_bf16(av[i], bv[j], acc[i][j], 0, 0, 0);
                __syncthreads();
            }
            #pragma unroll
            for (int i = 0; i < 4; ++i)
                #pragma unroll
                for (int j = 0; j < 4; ++j) {
                    int r0 = m0 + wm + i * 16 + (lane >> 4) * 4;
                    int cc = n0 + wn + j * 16 + lr;
                    #pragma unroll
                    for (int r = 0; r < 4; ++r)
                        outp[(size_t)(r0 + r) * 256 + cc] = acc[i][j][r];
                }
        }
    }
}

extern "C" void kernel_launch(void* const* d_in, const int* in_sizes, int n_in,
                              void* d_out, int out_size, void* d_ws, size_t ws_size,
                              hipStream_t stream) {
    const float* u0   = (const float*)d_in[0];
    const float* u1   = (const float*)d_in[1];
    const float* inw  = (const float*)d_in[2];
    const float* cxw  = (const float*)d_in[3];
    const float* czw  = (const float*)d_in[4];
    const float* xpw  = (const float*)d_in[5];
    const float* dtw  = (const float*)d_in[6];
    const float* dtb  = (const float*)d_in[7];
    const float* alog = (const float*)d_in[8];
    const float* Dp   = (const float*)d_in[9];
    const float* outw = (const float*)d_in[10];

    char* ws = (char*)d_ws;
    unsigned short* xz   = (unsigned short*)(ws + 0);          // 16,777,216
    unsigned short* xfb  = (unsigned short*)(ws + 16777216);   //  8,388,608
    float* delta         = (float*)(ws + 25165824);            // 16,777,216
    float* BC            = (float*)(ws + 41943040);            //  4,194,304
    unsigned short* catb = (unsigned short*)(ws + 46137344);   // 16,777,216
    float* P             = (float*)(ws + 62914560);            //  8,388,608
    float* H             = (float*)(ws + 71303168);            //  8,388,608
    float* An            = (float*)(ws + 79691776);            //      8,192
    unsigned short* Wcat = (unsigned short*)(ws + 79699968);   //     40,960 -> ~79.7 MB
    float* outp = (float*)d_out;

    void* args[] = { (void*)&u0, (void*)&u1, (void*)&inw, (void*)&cxw, (void*)&czw,
                     (void*)&xpw, (void*)&dtw, (void*)&dtb, (void*)&alog, (void*)&Dp,
                     (void*)&outw, (void*)&xz, (void*)&xfb, (void*)&delta, (void*)&BC,
                     (void*)&catb, (void*)&P, (void*)&H, (void*)&An, (void*)&Wcat,
                     (void*)&outp };

    int nb = 0;
    (void)hipOccupancyMaxActiveBlocksPerMultiprocessor(&nb, mega, 256, 0);
    int gridBlocks = (nb >= 2) ? 512 : 256;
    hipError_t e = hipLaunchCooperativeKernel((const void*)mega, dim3(gridBlocks),
                                              dim3(256), args, 0, stream);
    if (e != hipSuccess && gridBlocks == 512) {
        (void)hipLaunchCooperativeKernel((const void*)mega, dim3(256),
                                         dim3(256), args, 0, stream);
    }
}